// Round 1
// baseline (151.068 us; speedup 1.0000x reference)
//
#include <hip/hip_runtime.h>
#include <hip/hip_bf16.h>
#include <math.h>

// Problem constants (from reference setup_inputs):
//   N=6, B=2, H=12, T=1024, D=768, HEAD_DIM=64 -> scaling = 0.125
#define PN 6
#define PB 2
#define PH 12
#define PT 1024
#define PD 768

// ---------------------------------------------------------------------------
// Kernel 1: per (b,t) row compute e_scaled[n] = 0.125 * exp(a[n]) where
//   a = GELU_exact(RMSNorm(x) @ w1) @ w2 + bias
// One wave (64 lanes) per row. Output layout: e_ws[n * (B*T) + b*T + t]
// so that kernel 2 reads contiguous-t float4s per n-plane.
// ---------------------------------------------------------------------------
__global__ __launch_bounds__(64) void compute_e_kernel(
    const float* __restrict__ x,      // [B*T, D]
    const float* __restrict__ nw,     // [D]
    const float* __restrict__ w1,     // [D, N] row-major
    const float* __restrict__ w2,     // [N, N] row-major
    const float* __restrict__ bias,   // [N]
    float* __restrict__ e_out)        // [N, B*T]
{
    const int row  = blockIdx.x;          // 0 .. B*T-1
    const int lane = threadIdx.x;         // 0 .. 63
    const float* xr = x + (size_t)row * PD;

    // Each lane covers 12 strided elements (coalesced).
    float xs[12];
    float sumsq = 0.0f;
#pragma unroll
    for (int k = 0; k < 12; ++k) {
        float v = xr[lane + 64 * k];
        xs[k] = v;
        sumsq += v * v;
    }
    // wave-64 butterfly reduce
#pragma unroll
    for (int off = 32; off; off >>= 1) sumsq += __shfl_xor(sumsq, off, 64);

    const float eps = 1.1920928955078125e-07f;  // float32 machine eps
    const float inv = rsqrtf(sumsq * (1.0f / (float)PD) + eps);

    // partial dot products with w1 columns
    float p[PN] = {0.f, 0.f, 0.f, 0.f, 0.f, 0.f};
#pragma unroll
    for (int k = 0; k < 12; ++k) {
        const int d = lane + 64 * k;
        const float nv = xs[k] * inv * nw[d];
#pragma unroll
        for (int n = 0; n < PN; ++n) p[n] += nv * w1[d * PN + n];
    }
#pragma unroll
    for (int n = 0; n < PN; ++n) {
#pragma unroll
        for (int off = 32; off; off >>= 1) p[n] += __shfl_xor(p[n], off, 64);
    }

    if (lane == 0) {
        float g[PN];
#pragma unroll
        for (int n = 0; n < PN; ++n) {
            const float v = p[n];
            // exact GELU: 0.5*x*(1+erf(x/sqrt(2)))
            g[n] = 0.5f * v * (1.0f + erff(v * 0.7071067811865476f));
        }
#pragma unroll
        for (int j = 0; j < PN; ++j) {
            float a = bias[j];
#pragma unroll
            for (int n = 0; n < PN; ++n) a += g[n] * w2[n * PN + j];
            const float ev = 0.125f * expf(a);   // fold scaling = 1/sqrt(64)
            e_out[(size_t)j * (PB * PT) + row] = ev;
        }
    }
}

// ---------------------------------------------------------------------------
// Kernel 2: out[i] = sum_n qk[n*PLANE + i] * e[n, b(i), t(i)]
// Grid-stride over float4 output elements. qk streams are coalesced; the
// 48 KB e table lives in L1/L2.
// ---------------------------------------------------------------------------
__global__ __launch_bounds__(256) void combine_kernel(
    const float* __restrict__ qk,   // [N, B, H, T, T]
    const float* __restrict__ e,    // [N, B*T]
    float* __restrict__ out)        // [B, H, T, T]
{
    const size_t T4     = PT / 4;                         // 256
    const size_t PLANE4 = (size_t)PB * PH * PT * T4;      // 6,291,456
    const size_t BSTRIDE4 = (size_t)PH * PT * T4;         // 3,145,728 (per-b span)
    const float4* q4 = (const float4*)qk;
    const float4* e4 = (const float4*)e;                  // [n][ (b*T+t)/4 ]
    float4* o4 = (float4*)out;

    const size_t stride = (size_t)gridDim.x * blockDim.x;
    for (size_t i4 = (size_t)blockIdx.x * blockDim.x + threadIdx.x;
         i4 < PLANE4; i4 += stride) {
        const size_t t4 = i4 & (T4 - 1);
        const size_t b  = i4 / BSTRIDE4;                  // 0 or 1
        const size_t eb = b * T4 + t4;                    // (b*T)/4 + t4

        float4 acc = make_float4(0.f, 0.f, 0.f, 0.f);
#pragma unroll
        for (int n = 0; n < PN; ++n) {
            const float4 qv = q4[(size_t)n * PLANE4 + i4];
            const float4 ev = e4[(size_t)n * (PB * T4) + eb];
            acc.x += qv.x * ev.x;
            acc.y += qv.y * ev.y;
            acc.z += qv.z * ev.z;
            acc.w += qv.w * ev.w;
        }
        o4[i4] = acc;
    }
}

extern "C" void kernel_launch(void* const* d_in, const int* in_sizes, int n_in,
                              void* d_out, int out_size, void* d_ws, size_t ws_size,
                              hipStream_t stream) {
    const float* qk   = (const float*)d_in[0];  // [N,B,H,T,T]
    const float* x    = (const float*)d_in[1];  // [B,T,D]
    const float* nw   = (const float*)d_in[2];  // [D]
    const float* w1   = (const float*)d_in[3];  // [D,N]
    const float* w2   = (const float*)d_in[4];  // [N,N]
    const float* bias = (const float*)d_in[5];  // [N]
    float* out = (float*)d_out;

    float* e_ws = (float*)d_ws;                 // N*B*T floats = 48 KB

    // Kernel 1: one wave per (b,t) row
    compute_e_kernel<<<PB * PT, 64, 0, stream>>>(x, nw, w1, w2, bias, e_ws);

    // Kernel 2: grid-stride streaming combine
    combine_kernel<<<2048, 256, 0, stream>>>(qk, e_ws, out);
}

// Round 2
// 131.839 us; speedup vs baseline: 1.1459x; 1.1459x over previous
//
#include <hip/hip_runtime.h>
#include <hip/hip_bf16.h>
#include <math.h>

// Problem constants: N=6, B=2, H=12, T=1024, D=768, scaling = 1/sqrt(64) = 0.125
#define PN 6
#define PB 2
#define PH 12
#define PT 1024
#define PD 768

#define NBLOCKS 2048
#define NTHREADS 256

typedef float f4 __attribute__((ext_vector_type(4)));

// ---------------------------------------------------------------------------
// Kernel 1: per (b,t) row compute e_scaled[n] = 0.125 * exp(a[n]) where
//   a = GELU_exact(RMSNorm(x) @ w1) @ w2 + bias
// One wave (64 lanes) per row. Output layout: e_ws[n * (B*T) + b*T + t].
// ---------------------------------------------------------------------------
__global__ __launch_bounds__(64) void compute_e_kernel(
    const float* __restrict__ x,      // [B*T, D]
    const float* __restrict__ nw,     // [D]
    const float* __restrict__ w1,     // [D, N] row-major
    const float* __restrict__ w2,     // [N, N] row-major
    const float* __restrict__ bias,   // [N]
    float* __restrict__ e_out)        // [N, B*T]
{
    const int row  = blockIdx.x;          // 0 .. B*T-1
    const int lane = threadIdx.x;         // 0 .. 63
    const float* xr = x + (size_t)row * PD;

    float xs[12];
    float sumsq = 0.0f;
#pragma unroll
    for (int k = 0; k < 12; ++k) {
        float v = xr[lane + 64 * k];
        xs[k] = v;
        sumsq += v * v;
    }
#pragma unroll
    for (int off = 32; off; off >>= 1) sumsq += __shfl_xor(sumsq, off, 64);

    const float eps = 1.1920928955078125e-07f;  // float32 machine eps
    const float inv = rsqrtf(sumsq * (1.0f / (float)PD) + eps);

    float p[PN] = {0.f, 0.f, 0.f, 0.f, 0.f, 0.f};
#pragma unroll
    for (int k = 0; k < 12; ++k) {
        const int d = lane + 64 * k;
        const float nv = xs[k] * inv * nw[d];
#pragma unroll
        for (int n = 0; n < PN; ++n) p[n] += nv * w1[d * PN + n];
    }
#pragma unroll
    for (int n = 0; n < PN; ++n) {
#pragma unroll
        for (int off = 32; off; off >>= 1) p[n] += __shfl_xor(p[n], off, 64);
    }

    if (lane == 0) {
        float g[PN];
#pragma unroll
        for (int n = 0; n < PN; ++n) {
            const float v = p[n];
            g[n] = 0.5f * v * (1.0f + erff(v * 0.7071067811865476f));
        }
#pragma unroll
        for (int j = 0; j < PN; ++j) {
            float a = bias[j];
#pragma unroll
            for (int n = 0; n < PN; ++n) a += g[n] * w2[n * PN + j];
            e_out[(size_t)j * (PB * PT) + row] = 0.125f * expf(a);
        }
    }
}

// ---------------------------------------------------------------------------
// Kernel 2: out[i] = sum_n qk[n*PLANE + i] * e[n, b(i), t(i)]
// Structured so each thread's t4 is loop-invariant and b flips once:
//   stride = NBLOCKS*NTHREADS = 524288; per-b span = 6*stride exactly.
// e-values hoisted out of the hot loop; non-temporal qk loads + out stores.
// ---------------------------------------------------------------------------
__global__ __launch_bounds__(NTHREADS) void combine_kernel(
    const float* __restrict__ qk,   // [N, B, H, T, T]
    const float* __restrict__ e,    // [N, B*T]
    float* __restrict__ out)        // [B, H, T, T]
{
    const size_t T4       = PT / 4;                      // 256
    const size_t PLANE4   = (size_t)PB * PH * PT * T4;   // 6,291,456
    const size_t BSTRIDE4 = (size_t)PH * PT * T4;        // 3,145,728 = 6*stride
    const size_t stride   = (size_t)NBLOCKS * NTHREADS;  // 524,288

    const f4* q4 = (const f4*)qk;
    const f4* e4 = (const f4*)e;
    f4* o4 = (f4*)out;

    const size_t tid = (size_t)blockIdx.x * NTHREADS + threadIdx.x;
    const size_t t4  = tid & (T4 - 1);   // invariant: stride % 256 == 0

#pragma unroll
    for (int b = 0; b < PB; ++b) {
        // hoist e-table values for this (b, t4)
        f4 ev[PN];
#pragma unroll
        for (int n = 0; n < PN; ++n)
            ev[n] = e4[(size_t)n * (PB * T4) + (size_t)b * T4 + t4];

        const size_t end = (size_t)(b + 1) * BSTRIDE4;
#pragma unroll 2
        for (size_t i4 = (size_t)b * BSTRIDE4 + tid; i4 < end; i4 += stride) {
            f4 acc = (f4)(0.0f);
#pragma unroll
            for (int n = 0; n < PN; ++n) {
                const f4 qv = __builtin_nontemporal_load(&q4[(size_t)n * PLANE4 + i4]);
                acc += qv * ev[n];
            }
            __builtin_nontemporal_store(acc, &o4[i4]);
        }
    }
}

extern "C" void kernel_launch(void* const* d_in, const int* in_sizes, int n_in,
                              void* d_out, int out_size, void* d_ws, size_t ws_size,
                              hipStream_t stream) {
    const float* qk   = (const float*)d_in[0];  // [N,B,H,T,T]
    const float* x    = (const float*)d_in[1];  // [B,T,D]
    const float* nw   = (const float*)d_in[2];  // [D]
    const float* w1   = (const float*)d_in[3];  // [D,N]
    const float* w2   = (const float*)d_in[4];  // [N,N]
    const float* bias = (const float*)d_in[5];  // [N]
    float* out = (float*)d_out;

    float* e_ws = (float*)d_ws;                 // N*B*T floats = 48 KB

    compute_e_kernel<<<PB * PT, 64, 0, stream>>>(x, nw, w1, w2, bias, e_ws);
    combine_kernel<<<NBLOCKS, NTHREADS, 0, stream>>>(qk, e_ws, out);
}